// Round 3
// baseline (106.637 us; speedup 1.0000x reference)
//
#include <hip/hip_runtime.h>
#include <hip/hip_bf16.h>

// Node_EncodingBlock on MI355X. Inputs fp32, output fp32 (harness compares
// both sides rounded to bf16, 2% tolerance).
// Algebraic simplifications (audited against the reference):
//  - row_emb == 0  =>  q == 0  =>  dot == 0  => Wq, Wk unused.
//  - col_emb one-hot(idx) => v[b,m,h,:] = Wv[idx[b,m], h*16:...], idx[b,m]=perm[b, m&127].
//  - score ms2[b,h,n,m] = g_h(cost[b,n,m]) : per-head scalar MLP of cost only.
//  - PV over m=0..499 folds into 128 aggregated softmax weights (idx has period 128).
//  - demand branch: demand*(Wd@Wn_bot) + (bd@Wn_bot + bn_node), precomputed.

#define BN_EPS 1e-5f
// ws layout (float offsets) — ~3.1 MB
#define WS_ATT   0          // [2000][128]
#define WS_X1    256000     // [2000][128]
#define WS_X2    512000     // [2000][128]
#define WS_PERM  768000     // [4][128] int
#define WS_U     768512
#define WS_C0    768640
#define WS_SUM1  768768
#define WS_SQ1   768896
#define WS_SUM2  769024
#define WS_SQ2   769152

// ---- init: argsort perm, demand-projection vectors, zero BN accumulators --
__global__ __launch_bounds__(128) void k_init(const float* __restrict__ rnd,
                                              const float* __restrict__ Wd,
                                              const float* __restrict__ bd,
                                              const float* __restrict__ Wn,
                                              const float* __restrict__ bnn,
                                              float* __restrict__ ws) {
  const int t = threadIdx.x;
  const int b = blockIdx.x;
  if (b < 4) {
    // stable ascending argsort of 128 floats via rank counting
    __shared__ float v[128];
    __shared__ int ps[128];
    float vt = rnd[b * 128 + t];
    v[t] = vt;
    __syncthreads();
    int rank = 0;
    for (int j = 0; j < 128; ++j) {
      float vj = v[j];
      rank += (vj < vt) || (vj == vt && j < t);
    }
    ps[rank] = t;
    __syncthreads();
    ((int*)(ws + WS_PERM))[b * 128 + t] = ps[t];
  } else {
    float u = 0.f, c0 = 0.f;
    for (int e = 0; e < 128; ++e) {
      float wn = Wn[(128 + e) * 128 + t];
      u  = fmaf(Wd[e], wn, u);
      c0 = fmaf(bd[e], wn, c0);
    }
    ws[WS_U + t]  = u;
    ws[WS_C0 + t] = c0 + bnn[t];
    ws[WS_SUM1 + t] = 0.f; ws[WS_SQ1 + t] = 0.f;
    ws[WS_SUM2 + t] = 0.f; ws[WS_SQ2 + t] = 0.f;
  }
}

// ---- attention: one wave per (b,h,n) --------------------------------------
__global__ __launch_bounds__(256) void k_attn(const float* __restrict__ cost,
                                              const float* __restrict__ Wv,
                                              const float* __restrict__ mix1w,
                                              const float* __restrict__ mix1b,
                                              const float* __restrict__ mix2w,
                                              const float* __restrict__ mix2b,
                                              float* __restrict__ ws) {
  const int lane = threadIdx.x & 63;
  const int wid  = blockIdx.x * 4 + (threadIdx.x >> 6);  // 0..15999
  const int b = wid / 4000;
  int rem = wid - b * 4000;
  const int h = rem / 500;
  const int n = rem - h * 500;

  float w1e[16], b1e[16], w2e[16];
#pragma unroll
  for (int s = 0; s < 16; ++s) {
    w1e[s] = mix1w[h * 32 + 16 + s];  // mix1_w[h,1,s] (dot term is zero)
    b1e[s] = mix1b[h * 16 + s];
    w2e[s] = mix2w[h * 16 + s];
  }
  const float b2e = mix2b[h];

  const float* crow = cost + (size_t)(b * 500 + n) * 500;
  float sv[8];
  float mx = -1e30f;
#pragma unroll
  for (int ii = 0; ii < 8; ++ii) {
    int m = ii * 64 + lane;
    float c = (m < 500) ? crow[m] : 0.f;
    float s = b2e;
#pragma unroll
    for (int k = 0; k < 16; ++k) {
      float tt = fmaf(c, w1e[k], b1e[k]);
      tt = fmaxf(tt, 0.f);
      s = fmaf(tt, w2e[k], s);
    }
    if (m >= 500) s = -1e30f;
    sv[ii] = s;
    mx = fmaxf(mx, s);
  }
#pragma unroll
  for (int off = 32; off; off >>= 1) mx = fmaxf(mx, __shfl_xor(mx, off));

  // fold weights into aggregated weights: a0 (j=lane), a1 (j=lane+64)
  float a0 = 0.f, a1 = 0.f, wsum = 0.f;
#pragma unroll
  for (int ii = 0; ii < 8; ++ii) {
    float w = __expf(sv[ii] - mx);   // masked lanes -> 0
    wsum += w;
    if (ii & 1) a1 += w; else a0 += w;
  }

  const int* perm = (const int*)(ws + WS_PERM) + b * 128;
  int p0 = perm[lane];
  int p1 = perm[64 + lane];
  const float4* v0 = (const float4*)(Wv + p0 * 128 + h * 16);
  const float4* v1 = (const float4*)(Wv + p1 * 128 + h * 16);
  float acc[16];
#pragma unroll
  for (int q = 0; q < 4; ++q) {
    float4 x0 = v0[q], x1 = v1[q];
    acc[q * 4 + 0] = a0 * x0.x + a1 * x1.x;
    acc[q * 4 + 1] = a0 * x0.y + a1 * x1.y;
    acc[q * 4 + 2] = a0 * x0.z + a1 * x1.z;
    acc[q * 4 + 3] = a0 * x0.w + a1 * x1.w;
  }
#pragma unroll
  for (int off = 32; off; off >>= 1) {
    wsum += __shfl_xor(wsum, off);
#pragma unroll
    for (int d = 0; d < 16; ++d) acc[d] += __shfl_xor(acc[d], off);
  }
  float inv = 1.f / wsum;
  float oval = acc[0];
#pragma unroll
  for (int d = 1; d < 16; ++d) oval = (lane == d) ? acc[d] : oval;
  if (lane < 16)
    ws[WS_ATT + (size_t)(b * 500 + n) * 128 + h * 16 + lane] = oval * inv;
}

// ---- X1 = att @ Wo + bo ; fused BN1 statistics ----------------------------
__global__ __launch_bounds__(128) void k_mho(const float* __restrict__ Wo,
                                             const float* __restrict__ bo,
                                             float* __restrict__ ws) {
  __shared__ float sA[8][128];
  const int c = threadIdx.x;
  const int row0 = blockIdx.x * 8;
#pragma unroll
  for (int r = 0; r < 8; ++r) sA[r][c] = ws[WS_ATT + (row0 + r) * 128 + c];
  __syncthreads();
  float acc[8] = {};
  for (int k = 0; k < 128; ++k) {
    float wv = Wo[k * 128 + c];
#pragma unroll
    for (int r = 0; r < 8; ++r) acc[r] = fmaf(sA[r][k], wv, acc[r]);
  }
  float bc = bo[c];
  float s = 0.f, q = 0.f;
#pragma unroll
  for (int r = 0; r < 8; ++r) {
    float x = acc[r] + bc;
    ws[WS_X1 + (row0 + r) * 128 + c] = x;
    s += x; q = fmaf(x, x, q);
  }
  atomicAdd(ws + WS_SUM1 + c, s);
  atomicAdd(ws + WS_SQ1 + c, q);
}

// ---- BN1 -> out1 (LDS) -> Y=relu(out1@W1+b1) (LDS) -> X2=out1+Y@W2+b2 ; BN2 stats
__global__ __launch_bounds__(256) void k_ffn(const float* __restrict__ W1,
                                             const float* __restrict__ b1,
                                             const float* __restrict__ g1,
                                             const float* __restrict__ bb1,
                                             const float* __restrict__ W2,
                                             const float* __restrict__ b2,
                                             float* __restrict__ ws) {
  __shared__ float o1[8][128];
  __shared__ float sY[8][512];
  __shared__ float sc[128], sh[128];
  const int t = threadIdx.x;
  const int row0 = blockIdx.x * 8;
  if (t < 128) {
    float m = ws[WS_SUM1 + t] * 5e-4f;
    float v = ws[WS_SQ1 + t] * 5e-4f - m * m;
    float rs = rsqrtf(v + BN_EPS);
    float s = g1[t] * rs;
    sc[t] = s;
    sh[t] = bb1[t] - m * s;
  }
  __syncthreads();
  if (t < 128) {
#pragma unroll
    for (int r = 0; r < 8; ++r)
      o1[r][t] = ws[WS_X1 + (row0 + r) * 128 + t] * sc[t] + sh[t];
  }
  __syncthreads();
  float accA[8] = {}, accB[8] = {};
  for (int k = 0; k < 128; ++k) {
    float wa = W1[k * 512 + t];
    float wb = W1[k * 512 + t + 256];
#pragma unroll
    for (int r = 0; r < 8; ++r) {
      float ov = o1[r][k];
      accA[r] = fmaf(ov, wa, accA[r]);
      accB[r] = fmaf(ov, wb, accB[r]);
    }
  }
  float ba = b1[t], bb = b1[t + 256];
#pragma unroll
  for (int r = 0; r < 8; ++r) {
    sY[r][t]       = fmaxf(accA[r] + ba, 0.f);
    sY[r][t + 256] = fmaxf(accB[r] + bb, 0.f);
  }
  __syncthreads();
  const int c  = t & 127;
  const int rh = t >> 7;           // 0: rows 0..3, 1: rows 4..7
  float a4[4] = {};
  for (int k = 0; k < 512; ++k) {
    float wv = W2[k * 128 + c];
#pragma unroll
    for (int j = 0; j < 4; ++j) a4[j] = fmaf(sY[rh * 4 + j][k], wv, a4[j]);
  }
  float bc = b2[c];
  float s2 = 0.f, q2 = 0.f;
#pragma unroll
  for (int j = 0; j < 4; ++j) {
    float x = a4[j] + bc + o1[rh * 4 + j][c];
    ws[WS_X2 + (row0 + rh * 4 + j) * 128 + c] = x;
    s2 += x; q2 = fmaf(x, x, q2);
  }
  atomicAdd(ws + WS_SUM2 + c, s2);
  atomicAdd(ws + WS_SQ2 + c, q2);
}

// ---- out3 = BN2(X2); node = out3 @ Wn_top + demand*u + c0 ; fp32 store ----
__global__ __launch_bounds__(128) void k_final(const float* __restrict__ Wn,
                                               const float* __restrict__ g2,
                                               const float* __restrict__ bb2,
                                               const float* __restrict__ dem,
                                               float* __restrict__ out,
                                               float* __restrict__ ws) {
  __shared__ float o3[8][128];
  __shared__ float sc[128], sh[128];
  const int c = threadIdx.x;
  const int row0 = blockIdx.x * 8;
  {
    float m = ws[WS_SUM2 + c] * 5e-4f;
    float v = ws[WS_SQ2 + c] * 5e-4f - m * m;
    float rs = rsqrtf(v + BN_EPS);
    float s = g2[c] * rs;
    sc[c] = s;
    sh[c] = bb2[c] - m * s;
  }
  __syncthreads();
#pragma unroll
  for (int r = 0; r < 8; ++r)
    o3[r][c] = ws[WS_X2 + (row0 + r) * 128 + c] * sc[c] + sh[c];
  __syncthreads();
  float acc[8] = {};
  for (int k = 0; k < 128; ++k) {
    float wv = Wn[k * 128 + c];
#pragma unroll
    for (int r = 0; r < 8; ++r) acc[r] = fmaf(o3[r][k], wv, acc[r]);
  }
  float uc = ws[WS_U + c], c0c = ws[WS_C0 + c];
#pragma unroll
  for (int r = 0; r < 8; ++r)
    out[(row0 + r) * 128 + c] = acc[r] + dem[row0 + r] * uc + c0c;
}

extern "C" void kernel_launch(void* const* d_in, const int* in_sizes, int n_in,
                              void* d_out, int out_size, void* d_ws, size_t ws_size,
                              hipStream_t stream) {
  const float* cost   = (const float*)d_in[0];
  const float* dem    = (const float*)d_in[1];
  const float* rnd    = (const float*)d_in[2];
  // d_in[3] Wq, d_in[4] Wk unused (q == 0)
  const float* Wv     = (const float*)d_in[5];
  const float* mix1w  = (const float*)d_in[6];
  const float* mix1b  = (const float*)d_in[7];
  const float* mix2w  = (const float*)d_in[8];
  const float* mix2b  = (const float*)d_in[9];
  const float* Wo     = (const float*)d_in[10];
  const float* bo     = (const float*)d_in[11];
  const float* W1     = (const float*)d_in[12];
  const float* b1     = (const float*)d_in[13];
  const float* W2     = (const float*)d_in[14];
  const float* b2     = (const float*)d_in[15];
  const float* g1     = (const float*)d_in[16];
  const float* bb1    = (const float*)d_in[17];
  const float* g2     = (const float*)d_in[18];
  const float* bb2    = (const float*)d_in[19];
  const float* Wd     = (const float*)d_in[20];
  const float* bd     = (const float*)d_in[21];
  const float* Wn     = (const float*)d_in[22];
  const float* bnn    = (const float*)d_in[23];
  float* ws  = (float*)d_ws;
  float* out = (float*)d_out;

  hipLaunchKernelGGL(k_init,  dim3(5),    dim3(128), 0, stream, rnd, Wd, bd, Wn, bnn, ws);
  hipLaunchKernelGGL(k_attn,  dim3(4000), dim3(256), 0, stream, cost, Wv, mix1w, mix1b, mix2w, mix2b, ws);
  hipLaunchKernelGGL(k_mho,   dim3(250),  dim3(128), 0, stream, Wo, bo, ws);
  hipLaunchKernelGGL(k_ffn,   dim3(250),  dim3(256), 0, stream, W1, b1, g1, bb1, W2, b2, ws);
  hipLaunchKernelGGL(k_final, dim3(250),  dim3(128), 0, stream, Wn, g2, bb2, dem, out, ws);
}

// Round 4
// 95.508 us; speedup vs baseline: 1.1165x; 1.1165x over previous
//
#include <hip/hip_runtime.h>
#include <hip/hip_bf16.h>

// Node_EncodingBlock on MI355X. Inputs fp32, output fp32 (harness compares
// both sides rounded to bf16, 2% tolerance).
// Algebraic simplifications (audited against the reference):
//  - row_emb == 0  =>  q == 0  =>  dot == 0  => Wq, Wk unused.
//  - col_emb one-hot(idx) => v[b,m,h,:] = Wv[idx[b,m], h*16:...], idx[b,m]=perm[b, m&127].
//  - score ms2[b,h,n,m] = g_h(cost[b,n,m]) : per-head scalar MLP of cost only.
//  - PV over m=0..499 folds into 128 aggregated softmax weights (idx has period 128).
//  - demand branch: demand*(Wd@Wn_bot) + (bd@Wn_bot + bn_node), precomputed.
// R4: epilogue GEMMs restructured for latency hiding — float4 weight loads,
// 4-16 FMAs per load, unrolled independent loads (ILP), LDS-staged activations.

#define BN_EPS 1e-5f
// ws layout (float offsets) — ~3.1 MB
#define WS_ATT   0          // [2000][128]
#define WS_X1    256000     // [2000][128]
#define WS_X2    512000     // [2000][128]
#define WS_PERM  768000     // [4][128] int
#define WS_U     768512
#define WS_C0    768640
#define WS_SUM1  768768
#define WS_SQ1   768896
#define WS_SUM2  769024
#define WS_SQ2   769152

// ---- init: argsort perm, demand-projection vectors, zero BN accumulators --
__global__ __launch_bounds__(128) void k_init(const float* __restrict__ rnd,
                                              const float* __restrict__ Wd,
                                              const float* __restrict__ bd,
                                              const float* __restrict__ Wn,
                                              const float* __restrict__ bnn,
                                              float* __restrict__ ws) {
  const int t = threadIdx.x;
  const int b = blockIdx.x;
  if (b < 4) {
    __shared__ float v[128];
    __shared__ int ps[128];
    float vt = rnd[b * 128 + t];
    v[t] = vt;
    __syncthreads();
    int rank = 0;
    for (int j = 0; j < 128; ++j) {
      float vj = v[j];
      rank += (vj < vt) || (vj == vt && j < t);
    }
    ps[rank] = t;
    __syncthreads();
    ((int*)(ws + WS_PERM))[b * 128 + t] = ps[t];
  } else {
    float u = 0.f, c0 = 0.f;
    for (int e = 0; e < 128; ++e) {
      float wn = Wn[(128 + e) * 128 + t];
      u  = fmaf(Wd[e], wn, u);
      c0 = fmaf(bd[e], wn, c0);
    }
    ws[WS_U + t]  = u;
    ws[WS_C0 + t] = c0 + bnn[t];
    ws[WS_SUM1 + t] = 0.f; ws[WS_SQ1 + t] = 0.f;
    ws[WS_SUM2 + t] = 0.f; ws[WS_SQ2 + t] = 0.f;
  }
}

// ---- attention: one wave per (b,h,n) --------------------------------------
__global__ __launch_bounds__(256) void k_attn(const float* __restrict__ cost,
                                              const float* __restrict__ Wv,
                                              const float* __restrict__ mix1w,
                                              const float* __restrict__ mix1b,
                                              const float* __restrict__ mix2w,
                                              const float* __restrict__ mix2b,
                                              float* __restrict__ ws) {
  const int lane = threadIdx.x & 63;
  const int wid  = blockIdx.x * 4 + (threadIdx.x >> 6);  // 0..15999
  const int b = wid / 4000;
  int rem = wid - b * 4000;
  const int h = rem / 500;
  const int n = rem - h * 500;

  float w1e[16], b1e[16], w2e[16];
#pragma unroll
  for (int s = 0; s < 16; ++s) {
    w1e[s] = mix1w[h * 32 + 16 + s];  // mix1_w[h,1,s] (dot term is zero)
    b1e[s] = mix1b[h * 16 + s];
    w2e[s] = mix2w[h * 16 + s];
  }
  const float b2e = mix2b[h];

  const float* crow = cost + (size_t)(b * 500 + n) * 500;
  float sv[8];
  float mx = -1e30f;
#pragma unroll
  for (int ii = 0; ii < 8; ++ii) {
    int m = ii * 64 + lane;
    float c = (m < 500) ? crow[m] : 0.f;
    float s = b2e;
#pragma unroll
    for (int k = 0; k < 16; ++k) {
      float tt = fmaf(c, w1e[k], b1e[k]);
      tt = fmaxf(tt, 0.f);
      s = fmaf(tt, w2e[k], s);
    }
    if (m >= 500) s = -1e30f;
    sv[ii] = s;
    mx = fmaxf(mx, s);
  }
#pragma unroll
  for (int off = 32; off; off >>= 1) mx = fmaxf(mx, __shfl_xor(mx, off));

  float a0 = 0.f, a1 = 0.f, wsum = 0.f;
#pragma unroll
  for (int ii = 0; ii < 8; ++ii) {
    float w = __expf(sv[ii] - mx);   // masked lanes -> 0
    wsum += w;
    if (ii & 1) a1 += w; else a0 += w;
  }

  const int* perm = (const int*)(ws + WS_PERM) + b * 128;
  int p0 = perm[lane];
  int p1 = perm[64 + lane];
  const float4* v0 = (const float4*)(Wv + p0 * 128 + h * 16);
  const float4* v1 = (const float4*)(Wv + p1 * 128 + h * 16);
  float acc[16];
#pragma unroll
  for (int q = 0; q < 4; ++q) {
    float4 x0 = v0[q], x1 = v1[q];
    acc[q * 4 + 0] = a0 * x0.x + a1 * x1.x;
    acc[q * 4 + 1] = a0 * x0.y + a1 * x1.y;
    acc[q * 4 + 2] = a0 * x0.z + a1 * x1.z;
    acc[q * 4 + 3] = a0 * x0.w + a1 * x1.w;
  }
#pragma unroll
  for (int off = 32; off; off >>= 1) {
    wsum += __shfl_xor(wsum, off);
#pragma unroll
    for (int d = 0; d < 16; ++d) acc[d] += __shfl_xor(acc[d], off);
  }
  float inv = 1.f / wsum;
  float oval = acc[0];
#pragma unroll
  for (int d = 1; d < 16; ++d) oval = (lane == d) ? acc[d] : oval;
  if (lane < 16)
    ws[WS_ATT + (size_t)(b * 500 + n) * 128 + h * 16 + lane] = oval * inv;
}

// ---- X1 = att @ Wo + bo ; fused BN1 statistics ----------------------------
// 256 thr, 8 rows/block. thread = (cq = 4*(t&31) cols, rg = t>>5 row).
__global__ __launch_bounds__(256) void k_mho(const float* __restrict__ Wo,
                                             const float* __restrict__ bo,
                                             float* __restrict__ ws) {
  __shared__ float sA[8][128];
  __shared__ float sX[8][128];
  const int t = threadIdx.x;
  const int row0 = blockIdx.x * 8;
#pragma unroll
  for (int i = t; i < 1024; i += 256)
    sA[i >> 7][i & 127] = ws[WS_ATT + (size_t)(row0 + (i >> 7)) * 128 + (i & 127)];
  __syncthreads();
  const int cq = (t & 31) * 4;
  const int rg = t >> 5;
  float a0 = 0.f, a1 = 0.f, a2 = 0.f, a3 = 0.f;
#pragma unroll 8
  for (int k = 0; k < 128; ++k) {
    float4 w = *(const float4*)(Wo + k * 128 + cq);
    float a = sA[rg][k];
    a0 = fmaf(a, w.x, a0);
    a1 = fmaf(a, w.y, a1);
    a2 = fmaf(a, w.z, a2);
    a3 = fmaf(a, w.w, a3);
  }
  float4 bv = *(const float4*)(bo + cq);
  float4 x = {a0 + bv.x, a1 + bv.y, a2 + bv.z, a3 + bv.w};
  *(float4*)(ws + WS_X1 + (size_t)(row0 + rg) * 128 + cq) = x;
  __syncthreads();                 // all sA reads done
  *(float4*)&sX[rg][cq] = x;
  __syncthreads();
  if (t < 128) {
    float s = 0.f, q = 0.f;
#pragma unroll
    for (int r = 0; r < 8; ++r) { float xv = sX[r][t]; s += xv; q = fmaf(xv, xv, q); }
    atomicAdd(ws + WS_SUM1 + t, s);
    atomicAdd(ws + WS_SQ1 + t, q);
  }
}

// ---- BN1 -> o1 -> Y=relu(o1@W1+b1) -> X2=o1+Y@W2+b2 ; BN2 stats ----------
__global__ __launch_bounds__(256) void k_ffn(const float* __restrict__ W1,
                                             const float* __restrict__ b1,
                                             const float* __restrict__ g1,
                                             const float* __restrict__ bb1,
                                             const float* __restrict__ W2,
                                             const float* __restrict__ b2,
                                             float* __restrict__ ws) {
  __shared__ float o1[8][128];
  __shared__ float sY[8][512];
  __shared__ float sc[128], sh[128];
  const int t = threadIdx.x;
  const int row0 = blockIdx.x * 8;
  if (t < 128) {
    float m = ws[WS_SUM1 + t] * 5e-4f;
    float v = ws[WS_SQ1 + t] * 5e-4f - m * m;
    float rs = rsqrtf(v + BN_EPS);
    float s = g1[t] * rs;
    sc[t] = s;
    sh[t] = bb1[t] - m * s;
  }
  __syncthreads();
#pragma unroll
  for (int i = t; i < 1024; i += 256) {
    int r = i >> 7, c = i & 127;
    o1[r][c] = ws[WS_X1 + (size_t)(row0 + r) * 128 + c] * sc[c] + sh[c];
  }
  __syncthreads();
  // GEMM1: thread = (cq = 4*(t&127) of 512 cols, rg = 4*(t>>7) row base)
  {
    const int cq = (t & 127) * 4;
    const int rg = (t >> 7) * 4;
    float acc[4][4] = {};
#pragma unroll 4
    for (int k = 0; k < 128; ++k) {
      float4 w = *(const float4*)(W1 + (size_t)k * 512 + cq);
      float v0 = o1[rg + 0][k], v1 = o1[rg + 1][k];
      float v2 = o1[rg + 2][k], v3 = o1[rg + 3][k];
      acc[0][0] = fmaf(v0, w.x, acc[0][0]); acc[0][1] = fmaf(v0, w.y, acc[0][1]);
      acc[0][2] = fmaf(v0, w.z, acc[0][2]); acc[0][3] = fmaf(v0, w.w, acc[0][3]);
      acc[1][0] = fmaf(v1, w.x, acc[1][0]); acc[1][1] = fmaf(v1, w.y, acc[1][1]);
      acc[1][2] = fmaf(v1, w.z, acc[1][2]); acc[1][3] = fmaf(v1, w.w, acc[1][3]);
      acc[2][0] = fmaf(v2, w.x, acc[2][0]); acc[2][1] = fmaf(v2, w.y, acc[2][1]);
      acc[2][2] = fmaf(v2, w.z, acc[2][2]); acc[2][3] = fmaf(v2, w.w, acc[2][3]);
      acc[3][0] = fmaf(v3, w.x, acc[3][0]); acc[3][1] = fmaf(v3, w.y, acc[3][1]);
      acc[3][2] = fmaf(v3, w.z, acc[3][2]); acc[3][3] = fmaf(v3, w.w, acc[3][3]);
    }
    float4 bv = *(const float4*)(b1 + cq);
#pragma unroll
    for (int r = 0; r < 4; ++r) {
      float4 y = {fmaxf(acc[r][0] + bv.x, 0.f), fmaxf(acc[r][1] + bv.y, 0.f),
                  fmaxf(acc[r][2] + bv.z, 0.f), fmaxf(acc[r][3] + bv.w, 0.f)};
      *(float4*)&sY[rg + r][cq] = y;
    }
  }
  __syncthreads();
  // GEMM2: thread = (cq2 = 4*(t&31) of 128 cols, rg2 = t>>5 row)
  const int cq2 = (t & 31) * 4;
  const int rg2 = t >> 5;
  float a0 = 0.f, a1 = 0.f, a2 = 0.f, a3 = 0.f;
#pragma unroll 8
  for (int k = 0; k < 512; ++k) {
    float4 w = *(const float4*)(W2 + (size_t)k * 128 + cq2);
    float y = sY[rg2][k];
    a0 = fmaf(y, w.x, a0);
    a1 = fmaf(y, w.y, a1);
    a2 = fmaf(y, w.z, a2);
    a3 = fmaf(y, w.w, a3);
  }
  float4 bv2 = *(const float4*)(b2 + cq2);
  float4 x;
  x.x = a0 + bv2.x + o1[rg2][cq2 + 0];
  x.y = a1 + bv2.y + o1[rg2][cq2 + 1];
  x.z = a2 + bv2.z + o1[rg2][cq2 + 2];
  x.w = a3 + bv2.w + o1[rg2][cq2 + 3];
  *(float4*)(ws + WS_X2 + (size_t)(row0 + rg2) * 128 + cq2) = x;
  __syncthreads();                 // all sY reads done
  *(float4*)&sY[rg2][cq2] = x;     // reuse sY[.][0:128] as stats staging
  __syncthreads();
  if (t < 128) {
    float s = 0.f, q = 0.f;
#pragma unroll
    for (int r = 0; r < 8; ++r) { float xv = sY[r][t]; s += xv; q = fmaf(xv, xv, q); }
    atomicAdd(ws + WS_SUM2 + t, s);
    atomicAdd(ws + WS_SQ2 + t, q);
  }
}

// ---- out3 = BN2(X2); node = out3 @ Wn_top + demand*u + c0 ; fp32 store ----
__global__ __launch_bounds__(256) void k_final(const float* __restrict__ Wn,
                                               const float* __restrict__ g2,
                                               const float* __restrict__ bb2,
                                               const float* __restrict__ dem,
                                               float* __restrict__ out,
                                               float* __restrict__ ws) {
  __shared__ float o3[8][128];
  __shared__ float sc[128], sh[128];
  const int t = threadIdx.x;
  const int row0 = blockIdx.x * 8;
  if (t < 128) {
    float m = ws[WS_SUM2 + t] * 5e-4f;
    float v = ws[WS_SQ2 + t] * 5e-4f - m * m;
    float rs = rsqrtf(v + BN_EPS);
    float s = g2[t] * rs;
    sc[t] = s;
    sh[t] = bb2[t] - m * s;
  }
  __syncthreads();
#pragma unroll
  for (int i = t; i < 1024; i += 256) {
    int r = i >> 7, c = i & 127;
    o3[r][c] = ws[WS_X2 + (size_t)(row0 + r) * 128 + c] * sc[c] + sh[c];
  }
  __syncthreads();
  const int cq = (t & 31) * 4;
  const int rg = t >> 5;
  float a0 = 0.f, a1 = 0.f, a2 = 0.f, a3 = 0.f;
#pragma unroll 8
  for (int k = 0; k < 128; ++k) {
    float4 w = *(const float4*)(Wn + (size_t)k * 128 + cq);
    float a = o3[rg][k];
    a0 = fmaf(a, w.x, a0);
    a1 = fmaf(a, w.y, a1);
    a2 = fmaf(a, w.z, a2);
    a3 = fmaf(a, w.w, a3);
  }
  float4 u4 = *(const float4*)(ws + WS_U + cq);
  float4 c4 = *(const float4*)(ws + WS_C0 + cq);
  float dv = dem[row0 + rg];
  float4 o;
  o.x = a0 + dv * u4.x + c4.x;
  o.y = a1 + dv * u4.y + c4.y;
  o.z = a2 + dv * u4.z + c4.z;
  o.w = a3 + dv * u4.w + c4.w;
  *(float4*)(out + (size_t)(row0 + rg) * 128 + cq) = o;
}

extern "C" void kernel_launch(void* const* d_in, const int* in_sizes, int n_in,
                              void* d_out, int out_size, void* d_ws, size_t ws_size,
                              hipStream_t stream) {
  const float* cost   = (const float*)d_in[0];
  const float* dem    = (const float*)d_in[1];
  const float* rnd    = (const float*)d_in[2];
  // d_in[3] Wq, d_in[4] Wk unused (q == 0)
  const float* Wv     = (const float*)d_in[5];
  const float* mix1w  = (const float*)d_in[6];
  const float* mix1b  = (const float*)d_in[7];
  const float* mix2w  = (const float*)d_in[8];
  const float* mix2b  = (const float*)d_in[9];
  const float* Wo     = (const float*)d_in[10];
  const float* bo     = (const float*)d_in[11];
  const float* W1     = (const float*)d_in[12];
  const float* b1     = (const float*)d_in[13];
  const float* W2     = (const float*)d_in[14];
  const float* b2     = (const float*)d_in[15];
  const float* g1     = (const float*)d_in[16];
  const float* bb1    = (const float*)d_in[17];
  const float* g2     = (const float*)d_in[18];
  const float* bb2    = (const float*)d_in[19];
  const float* Wd     = (const float*)d_in[20];
  const float* bd     = (const float*)d_in[21];
  const float* Wn     = (const float*)d_in[22];
  const float* bnn    = (const float*)d_in[23];
  float* ws  = (float*)d_ws;
  float* out = (float*)d_out;

  hipLaunchKernelGGL(k_init,  dim3(5),    dim3(128), 0, stream, rnd, Wd, bd, Wn, bnn, ws);
  hipLaunchKernelGGL(k_attn,  dim3(4000), dim3(256), 0, stream, cost, Wv, mix1w, mix1b, mix2w, mix2b, ws);
  hipLaunchKernelGGL(k_mho,   dim3(250),  dim3(256), 0, stream, Wo, bo, ws);
  hipLaunchKernelGGL(k_ffn,   dim3(250),  dim3(256), 0, stream, W1, b1, g1, bb1, W2, b2, ws);
  hipLaunchKernelGGL(k_final, dim3(250),  dim3(256), 0, stream, Wn, g2, bb2, dem, out, ws);
}

// Round 5
// 78.108 us; speedup vs baseline: 1.3652x; 1.2228x over previous
//
#include <hip/hip_runtime.h>
#include <hip/hip_bf16.h>

// Node_EncodingBlock on MI355X. Inputs fp32, output fp32 (harness compares
// both sides rounded to bf16, 2% tolerance).
// Algebraic simplifications (audited against the reference):
//  - row_emb == 0  =>  q == 0  =>  dot == 0  => Wq, Wk unused.
//  - col_emb one-hot(idx) => v[b,m,h,:] = Wv[idx[b,m], h*16:...], idx[b,m]=perm[b, m&127].
//  - score ms2[b,h,n,m] = g_h(cost[b,n,m]) : per-head scalar MLP of cost only.
//  - PV over m=0..499 folds into 128 aggregated softmax weights (idx has period 128).
//  - demand branch: demand*(Wd@Wn_bot) + (bd@Wn_bot + bn_node), precomputed.
// R5: epilogue GEMMs — explicit 8-deep register load batches (VGPR=36 in R4
// showed the compiler kept ~1 load in flight -> one L2 round-trip per k).
// K-split across thread groups + LDS partial reduce: weights read once/block,
// 16 FMA per float4 load. 4 rows/block -> 500 blocks (2/CU, 8 waves/CU).

#define BN_EPS 1e-5f
// ws layout (float offsets) — ~3.1 MB
#define WS_ATT   0          // [2000][128]
#define WS_X1    256000     // [2000][128]
#define WS_X2    512000     // [2000][128]
#define WS_PERM  768000     // [4][128] int
#define WS_U     768512
#define WS_C0    768640
#define WS_SUM1  768768
#define WS_SQ1   768896
#define WS_SUM2  769024
#define WS_SQ2   769152

// ---- init: argsort perm, demand-projection vectors, zero BN accumulators --
__global__ __launch_bounds__(128) void k_init(const float* __restrict__ rnd,
                                              const float* __restrict__ Wd,
                                              const float* __restrict__ bd,
                                              const float* __restrict__ Wn,
                                              const float* __restrict__ bnn,
                                              float* __restrict__ ws) {
  const int t = threadIdx.x;
  const int b = blockIdx.x;
  if (b < 4) {
    __shared__ float v[128];
    __shared__ int ps[128];
    float vt = rnd[b * 128 + t];
    v[t] = vt;
    __syncthreads();
    int rank = 0;
    for (int j = 0; j < 128; ++j) {
      float vj = v[j];
      rank += (vj < vt) || (vj == vt && j < t);
    }
    ps[rank] = t;
    __syncthreads();
    ((int*)(ws + WS_PERM))[b * 128 + t] = ps[t];
  } else {
    float u = 0.f, c0 = 0.f;
#pragma unroll 8
    for (int e = 0; e < 128; ++e) {
      float wn = Wn[(128 + e) * 128 + t];
      u  = fmaf(Wd[e], wn, u);
      c0 = fmaf(bd[e], wn, c0);
    }
    ws[WS_U + t]  = u;
    ws[WS_C0 + t] = c0 + bnn[t];
    ws[WS_SUM1 + t] = 0.f; ws[WS_SQ1 + t] = 0.f;
    ws[WS_SUM2 + t] = 0.f; ws[WS_SQ2 + t] = 0.f;
  }
}

// ---- attention: one wave per (b,h,n) --------------------------------------
__global__ __launch_bounds__(256) void k_attn(const float* __restrict__ cost,
                                              const float* __restrict__ Wv,
                                              const float* __restrict__ mix1w,
                                              const float* __restrict__ mix1b,
                                              const float* __restrict__ mix2w,
                                              const float* __restrict__ mix2b,
                                              float* __restrict__ ws) {
  const int lane = threadIdx.x & 63;
  const int wid  = blockIdx.x * 4 + (threadIdx.x >> 6);  // 0..15999
  const int b = wid / 4000;
  int rem = wid - b * 4000;
  const int h = rem / 500;
  const int n = rem - h * 500;

  float w1e[16], b1e[16], w2e[16];
#pragma unroll
  for (int s = 0; s < 16; ++s) {
    w1e[s] = mix1w[h * 32 + 16 + s];  // mix1_w[h,1,s] (dot term is zero)
    b1e[s] = mix1b[h * 16 + s];
    w2e[s] = mix2w[h * 16 + s];
  }
  const float b2e = mix2b[h];

  const float* crow = cost + (size_t)(b * 500 + n) * 500;
  float sv[8];
  float mx = -1e30f;
#pragma unroll
  for (int ii = 0; ii < 8; ++ii) {
    int m = ii * 64 + lane;
    float c = (m < 500) ? crow[m] : 0.f;
    float s = b2e;
#pragma unroll
    for (int k = 0; k < 16; ++k) {
      float tt = fmaf(c, w1e[k], b1e[k]);
      tt = fmaxf(tt, 0.f);
      s = fmaf(tt, w2e[k], s);
    }
    if (m >= 500) s = -1e30f;
    sv[ii] = s;
    mx = fmaxf(mx, s);
  }
#pragma unroll
  for (int off = 32; off; off >>= 1) mx = fmaxf(mx, __shfl_xor(mx, off));

  float a0 = 0.f, a1 = 0.f, wsum = 0.f;
#pragma unroll
  for (int ii = 0; ii < 8; ++ii) {
    float w = __expf(sv[ii] - mx);   // masked lanes -> 0
    wsum += w;
    if (ii & 1) a1 += w; else a0 += w;
  }

  const int* perm = (const int*)(ws + WS_PERM) + b * 128;
  int p0 = perm[lane];
  int p1 = perm[64 + lane];
  const float4* v0 = (const float4*)(Wv + p0 * 128 + h * 16);
  const float4* v1 = (const float4*)(Wv + p1 * 128 + h * 16);
  float acc[16];
#pragma unroll
  for (int q = 0; q < 4; ++q) {
    float4 x0 = v0[q], x1 = v1[q];
    acc[q * 4 + 0] = a0 * x0.x + a1 * x1.x;
    acc[q * 4 + 1] = a0 * x0.y + a1 * x1.y;
    acc[q * 4 + 2] = a0 * x0.z + a1 * x1.z;
    acc[q * 4 + 3] = a0 * x0.w + a1 * x1.w;
  }
#pragma unroll
  for (int off = 32; off; off >>= 1) {
    wsum += __shfl_xor(wsum, off);
#pragma unroll
    for (int d = 0; d < 16; ++d) acc[d] += __shfl_xor(acc[d], off);
  }
  float inv = 1.f / wsum;
  float oval = acc[0];
#pragma unroll
  for (int d = 1; d < 16; ++d) oval = (lane == d) ? acc[d] : oval;
  if (lane < 16)
    ws[WS_ATT + (size_t)(b * 500 + n) * 128 + h * 16 + lane] = oval * inv;
}

// Batched GEMM micro-step: 8 float4 weight loads into named regs, then
// 4 rows x 4 cols x 8 k FMAs. All indices static after unroll.
#define GEMM_BATCH8(WPTR, LDW, KIDX, ACT2D, ACC)                        \
  {                                                                     \
    float4 w[8];                                                        \
    _Pragma("unroll")                                                   \
    for (int u = 0; u < 8; ++u)                                         \
      w[u] = *(const float4*)((WPTR) + (size_t)((KIDX) + u) * (LDW));   \
    _Pragma("unroll")                                                   \
    for (int u = 0; u < 8; ++u) {                                       \
      _Pragma("unroll")                                                 \
      for (int r = 0; r < 4; ++r) {                                     \
        float a = ACT2D[r][u];                                          \
        ACC[r][0] = fmaf(a, w[u].x, ACC[r][0]);                         \
        ACC[r][1] = fmaf(a, w[u].y, ACC[r][1]);                         \
        ACC[r][2] = fmaf(a, w[u].z, ACC[r][2]);                         \
        ACC[r][3] = fmaf(a, w[u].w, ACC[r][3]);                         \
      }                                                                 \
    }                                                                   \
  }

#define LOAD_ACT8(SRC2D, KIDX, ACT2D)                                   \
  {                                                                     \
    _Pragma("unroll")                                                   \
    for (int r = 0; r < 4; ++r) {                                       \
      float4 x = *(const float4*)&SRC2D[r][(KIDX)];                     \
      float4 y = *(const float4*)&SRC2D[r][(KIDX) + 4];                 \
      ACT2D[r][0] = x.x; ACT2D[r][1] = x.y; ACT2D[r][2] = x.z;          \
      ACT2D[r][3] = x.w; ACT2D[r][4] = y.x; ACT2D[r][5] = y.y;          \
      ACT2D[r][6] = y.z; ACT2D[r][7] = y.w;                             \
    }                                                                   \
  }

// ---- X1 = att @ Wo + bo ; fused BN1 statistics ----------------------------
// 500 blocks x 256 thr, 4 rows/block. thread = 4 rows x 4 cols x 16 k (8 k-segs).
__global__ __launch_bounds__(256) void k_mho(const float* __restrict__ Wo,
                                             const float* __restrict__ bo,
                                             float* __restrict__ ws) {
  __shared__ float sA[4][128];
  __shared__ float sP[8][512];
  __shared__ float sS[256], sQ[256];
  const int t = threadIdx.x;
  const int row0 = blockIdx.x * 4;
#pragma unroll
  for (int i = t; i < 512; i += 256)
    sA[i >> 7][i & 127] = ws[WS_ATT + (size_t)(row0 + (i >> 7)) * 128 + (i & 127)];
  __syncthreads();
  const int cg  = (t & 31) * 4;
  const int seg = t >> 5;
  const int k0  = seg * 16;
  float acc[4][4] = {};
  float av[4][8];
#pragma unroll
  for (int kb = 0; kb < 16; kb += 8) {
    LOAD_ACT8(sA, k0 + kb, av);
    GEMM_BATCH8(Wo + cg, 128, k0 + kb, av, acc);
  }
#pragma unroll
  for (int r = 0; r < 4; ++r)
    *(float4*)&sP[seg][r * 128 + cg] = *(float4*)acc[r];
  __syncthreads();
  float s = 0.f, q = 0.f;
#pragma unroll
  for (int pass = 0; pass < 2; ++pass) {
    int idx = t + pass * 256;
    int col = idx & 127, r = idx >> 7;
    float x = bo[col];
#pragma unroll
    for (int sg = 0; sg < 8; ++sg) x += sP[sg][idx & 511];
    ws[WS_X1 + (size_t)(row0 + r) * 128 + col] = x;
    s += x; q = fmaf(x, x, q);
  }
  sS[t] = s; sQ[t] = q;
  __syncthreads();
  if (t < 128) {
    atomicAdd(ws + WS_SUM1 + t, sS[t] + sS[t + 128]);
    atomicAdd(ws + WS_SQ1 + t, sQ[t] + sQ[t + 128]);
  }
}

// ---- BN1 -> o1 -> Y=relu(o1@W1+b1) -> X2=o1+Y@W2+b2 ; BN2 stats ----------
// 500 blocks x 256 thr, 4 rows/block.
__global__ __launch_bounds__(256) void k_ffn(const float* __restrict__ W1,
                                             const float* __restrict__ b1,
                                             const float* __restrict__ g1,
                                             const float* __restrict__ bb1,
                                             const float* __restrict__ W2,
                                             const float* __restrict__ b2,
                                             float* __restrict__ ws) {
  __shared__ float o1[4][128];
  __shared__ float sY[4][512];
  __shared__ float sP[8][512];
  __shared__ float sc[128], sh[128];
  __shared__ float sS[256], sQ[256];
  const int t = threadIdx.x;
  const int row0 = blockIdx.x * 4;
  if (t < 128) {
    float m = ws[WS_SUM1 + t] * 5e-4f;
    float v = ws[WS_SQ1 + t] * 5e-4f - m * m;
    float rs = rsqrtf(v + BN_EPS);
    float s = g1[t] * rs;
    sc[t] = s;
    sh[t] = bb1[t] - m * s;
  }
  __syncthreads();
#pragma unroll
  for (int i = t; i < 512; i += 256) {
    int r = i >> 7, c = i & 127;
    o1[r][c] = ws[WS_X1 + (size_t)(row0 + r) * 128 + c] * sc[c] + sh[c];
  }
  __syncthreads();
  // GEMM1: 128 col-groups x 2 k-segs; thread = 4 rows x 4 cols x 64 k.
  {
    const int cg   = (t & 127) * 4;
    const int kseg = t >> 7;
    const int kb0  = kseg * 64;
    float acc[4][4] = {};
    float av[4][8];
#pragma unroll
    for (int k0 = 0; k0 < 64; k0 += 8) {
      LOAD_ACT8(o1, kb0 + k0, av);
      GEMM_BATCH8(W1 + cg, 512, kb0 + k0, av, acc);
    }
    float* pf = &sP[0][0];  // [4][512] partial for kseg1
    if (kseg == 1) {
#pragma unroll
      for (int r = 0; r < 4; ++r)
        *(float4*)(pf + r * 512 + cg) = *(float4*)acc[r];
    }
    __syncthreads();
    if (kseg == 0) {
      float4 bv = *(const float4*)(b1 + cg);
#pragma unroll
      for (int r = 0; r < 4; ++r) {
        float4 p = *(float4*)(pf + r * 512 + cg);
        float4 y = {fmaxf(acc[r][0] + p.x + bv.x, 0.f),
                    fmaxf(acc[r][1] + p.y + bv.y, 0.f),
                    fmaxf(acc[r][2] + p.z + bv.z, 0.f),
                    fmaxf(acc[r][3] + p.w + bv.w, 0.f)};
        *(float4*)&sY[r][cg] = y;
      }
    }
  }
  __syncthreads();
  // GEMM2: 32 col-groups x 8 k-segs; thread = 4 rows x 4 cols x 64 k.
  {
    const int cg  = (t & 31) * 4;
    const int seg = t >> 5;
    const int k0  = seg * 64;
    float acc[4][4] = {};
    float av[4][8];
#pragma unroll
    for (int kb = 0; kb < 64; kb += 8) {
      LOAD_ACT8(sY, k0 + kb, av);
      GEMM_BATCH8(W2 + cg, 128, k0 + kb, av, acc);
    }
    __syncthreads();   // sP GEMM1 reads done (kseg0 path) before overwrite
#pragma unroll
    for (int r = 0; r < 4; ++r)
      *(float4*)&sP[seg][r * 128 + cg] = *(float4*)acc[r];
  }
  __syncthreads();
  float s = 0.f, q = 0.f;
#pragma unroll
  for (int pass = 0; pass < 2; ++pass) {
    int idx = t + pass * 256;
    int col = idx & 127, r = idx >> 7;
    float x = b2[col] + o1[r][col];
#pragma unroll
    for (int sg = 0; sg < 8; ++sg) x += sP[sg][idx & 511];
    ws[WS_X2 + (size_t)(row0 + r) * 128 + col] = x;
    s += x; q = fmaf(x, x, q);
  }
  sS[t] = s; sQ[t] = q;
  __syncthreads();
  if (t < 128) {
    atomicAdd(ws + WS_SUM2 + t, sS[t] + sS[t + 128]);
    atomicAdd(ws + WS_SQ2 + t, sQ[t] + sQ[t + 128]);
  }
}

// ---- out3 = BN2(X2); node = out3 @ Wn_top + demand*u + c0 ; fp32 store ----
// 500 blocks x 256 thr, 4 rows/block; same k-split-8 structure as k_mho.
__global__ __launch_bounds__(256) void k_final(const float* __restrict__ Wn,
                                               const float* __restrict__ g2,
                                               const float* __restrict__ bb2,
                                               const float* __restrict__ dem,
                                               float* __restrict__ out,
                                               float* __restrict__ ws) {
  __shared__ float o3[4][128];
  __shared__ float sP[8][512];
  __shared__ float sc[128], sh[128];
  const int t = threadIdx.x;
  const int row0 = blockIdx.x * 4;
  if (t < 128) {
    float m = ws[WS_SUM2 + t] * 5e-4f;
    float v = ws[WS_SQ2 + t] * 5e-4f - m * m;
    float rs = rsqrtf(v + BN_EPS);
    float s = g2[t] * rs;
    sc[t] = s;
    sh[t] = bb2[t] - m * s;
  }
  __syncthreads();
#pragma unroll
  for (int i = t; i < 512; i += 256) {
    int r = i >> 7, c = i & 127;
    o3[r][c] = ws[WS_X2 + (size_t)(row0 + r) * 128 + c] * sc[c] + sh[c];
  }
  __syncthreads();
  const int cg  = (t & 31) * 4;
  const int seg = t >> 5;
  const int k0  = seg * 16;
  float acc[4][4] = {};
  float av[4][8];
#pragma unroll
  for (int kb = 0; kb < 16; kb += 8) {
    LOAD_ACT8(o3, k0 + kb, av);
    GEMM_BATCH8(Wn + cg, 128, k0 + kb, av, acc);
  }
#pragma unroll
  for (int r = 0; r < 4; ++r)
    *(float4*)&sP[seg][r * 128 + cg] = *(float4*)acc[r];
  __syncthreads();
#pragma unroll
  for (int pass = 0; pass < 2; ++pass) {
    int idx = t + pass * 256;
    int col = idx & 127, r = idx >> 7;
    float x = ws[WS_C0 + col] + dem[row0 + r] * ws[WS_U + col];
#pragma unroll
    for (int sg = 0; sg < 8; ++sg) x += sP[sg][idx & 511];
    out[(size_t)(row0 + r) * 128 + col] = x;
  }
}

extern "C" void kernel_launch(void* const* d_in, const int* in_sizes, int n_in,
                              void* d_out, int out_size, void* d_ws, size_t ws_size,
                              hipStream_t stream) {
  const float* cost   = (const float*)d_in[0];
  const float* dem    = (const float*)d_in[1];
  const float* rnd    = (const float*)d_in[2];
  // d_in[3] Wq, d_in[4] Wk unused (q == 0)
  const float* Wv     = (const float*)d_in[5];
  const float* mix1w  = (const float*)d_in[6];
  const float* mix1b  = (const float*)d_in[7];
  const float* mix2w  = (const float*)d_in[8];
  const float* mix2b  = (const float*)d_in[9];
  const float* Wo     = (const float*)d_in[10];
  const float* bo     = (const float*)d_in[11];
  const float* W1     = (const float*)d_in[12];
  const float* b1     = (const float*)d_in[13];
  const float* W2     = (const float*)d_in[14];
  const float* b2     = (const float*)d_in[15];
  const float* g1     = (const float*)d_in[16];
  const float* bb1    = (const float*)d_in[17];
  const float* g2     = (const float*)d_in[18];
  const float* bb2    = (const float*)d_in[19];
  const float* Wd     = (const float*)d_in[20];
  const float* bd     = (const float*)d_in[21];
  const float* Wn     = (const float*)d_in[22];
  const float* bnn    = (const float*)d_in[23];
  float* ws  = (float*)d_ws;
  float* out = (float*)d_out;

  hipLaunchKernelGGL(k_init,  dim3(5),    dim3(128), 0, stream, rnd, Wd, bd, Wn, bnn, ws);
  hipLaunchKernelGGL(k_attn,  dim3(4000), dim3(256), 0, stream, cost, Wv, mix1w, mix1b, mix2w, mix2b, ws);
  hipLaunchKernelGGL(k_mho,   dim3(500),  dim3(256), 0, stream, Wo, bo, ws);
  hipLaunchKernelGGL(k_ffn,   dim3(500),  dim3(256), 0, stream, W1, b1, g1, bb1, W2, b2, ws);
  hipLaunchKernelGGL(k_final, dim3(500),  dim3(256), 0, stream, Wn, g2, bb2, dem, out, ws);
}

// Round 6
// 60.860 us; speedup vs baseline: 1.7522x; 1.2834x over previous
//
#include <hip/hip_runtime.h>
#include <hip/hip_bf16.h>

// Node_EncodingBlock on MI355X. Inputs fp32, output fp32 (harness compares
// both sides rounded to bf16, 2% tolerance).
// Algebraic simplifications (audited against the reference):
//  - row_emb == 0  =>  q == 0  =>  dot == 0  => Wq, Wk unused.
//  - col_emb one-hot(idx) => v[b,m,h,:] = Wv[idx[b,m], h*16:...], idx[b,m]=perm[b, m&127].
//  - score ms2[b,h,n,m] = g_h(cost[b,n,m]) : per-head scalar MLP of cost only.
//  - PV over m=0..499 folds into 128 aggregated softmax weights (idx has period 128).
//  - demand branch: demand*(Wd@Wn_bot) + (bd@Wn_bot + bn_node), precomputed.
// R6: fuse attn+mho (aggregated-weight LDS matvec replaces 96-shuffle reduce,
// kills WS_ATT roundtrip); k_ffn 8 rows/block x 512 thr (halves W1/W2 traffic).

#define BN_EPS 1e-5f
// ws layout (float offsets)
#define WS_X1    256000     // [2000][128]
#define WS_X2    512000     // [2000][128]
#define WS_PERM  768000     // [4][128] int
#define WS_U     768512
#define WS_C0    768640
#define WS_SUM1  768768
#define WS_SQ1   768896
#define WS_SUM2  769024
#define WS_SQ2   769152

// ---- init: argsort perm, demand-projection vectors, zero BN accumulators --
__global__ __launch_bounds__(128) void k_init(const float* __restrict__ rnd,
                                              const float* __restrict__ Wd,
                                              const float* __restrict__ bd,
                                              const float* __restrict__ Wn,
                                              const float* __restrict__ bnn,
                                              float* __restrict__ ws) {
  const int t = threadIdx.x;
  const int b = blockIdx.x;
  if (b < 4) {
    __shared__ float v[128];
    __shared__ int ps[128];
    float vt = rnd[b * 128 + t];
    v[t] = vt;
    __syncthreads();
    int rank = 0;
    for (int j = 0; j < 128; ++j) {
      float vj = v[j];
      rank += (vj < vt) || (vj == vt && j < t);
    }
    ps[rank] = t;
    __syncthreads();
    ((int*)(ws + WS_PERM))[b * 128 + t] = ps[t];
  } else {
    float u = 0.f, c0 = 0.f;
#pragma unroll 8
    for (int e = 0; e < 128; ++e) {
      float wn = Wn[(128 + e) * 128 + t];
      u  = fmaf(Wd[e], wn, u);
      c0 = fmaf(bd[e], wn, c0);
    }
    ws[WS_U + t]  = u;
    ws[WS_C0 + t] = c0 + bnn[t];
    ws[WS_SUM1 + t] = 0.f; ws[WS_SQ1 + t] = 0.f;
    ws[WS_SUM2 + t] = 0.f; ws[WS_SQ2 + t] = 0.f;
  }
}

// Batched GEMM micro-step: 8 float4 weight loads into named regs, then
// 4 rows x 4 cols x 8 k FMAs. All indices static after unroll.
#define GEMM_BATCH8(WPTR, LDW, KIDX, ACT2D, ACC)                        \
  {                                                                     \
    float4 w[8];                                                        \
    _Pragma("unroll")                                                   \
    for (int u = 0; u < 8; ++u)                                         \
      w[u] = *(const float4*)((WPTR) + (size_t)((KIDX) + u) * (LDW));   \
    _Pragma("unroll")                                                   \
    for (int u = 0; u < 8; ++u) {                                       \
      _Pragma("unroll")                                                 \
      for (int r = 0; r < 4; ++r) {                                     \
        float a = ACT2D[r][u];                                          \
        ACC[r][0] = fmaf(a, w[u].x, ACC[r][0]);                         \
        ACC[r][1] = fmaf(a, w[u].y, ACC[r][1]);                         \
        ACC[r][2] = fmaf(a, w[u].z, ACC[r][2]);                         \
        ACC[r][3] = fmaf(a, w[u].w, ACC[r][3]);                         \
      }                                                                 \
    }                                                                   \
  }

#define LOAD_ACT8(SRC2D, KIDX, ACT2D)                                   \
  {                                                                     \
    _Pragma("unroll")                                                   \
    for (int r = 0; r < 4; ++r) {                                       \
      float4 x = *(const float4*)&SRC2D[r][(KIDX)];                     \
      float4 y = *(const float4*)&SRC2D[r][(KIDX) + 4];                 \
      ACT2D[r][0] = x.x; ACT2D[r][1] = x.y; ACT2D[r][2] = x.z;          \
      ACT2D[r][3] = x.w; ACT2D[r][4] = y.x; ACT2D[r][5] = y.y;          \
      ACT2D[r][6] = y.z; ACT2D[r][7] = y.w;                             \
    }                                                                   \
  }

// ---- fused attention + multi_head_combine + BN1 stats --------------------
// 500 blocks x 256 thr, 4 rows/block (all rows of a block share batch b).
// Wave w owns row w: per head, score-MLP over 500 m (cost staged in LDS),
// softmax, writes 128 aggregated weights aw[r*8+h][j] (pre-divided by wsum).
// Then out_concat = aw-weighted Wv-row sums (coalesced), X1 = oc @ Wo + bo.
__global__ __launch_bounds__(256) void k_attn_mho(const float* __restrict__ cost,
                                                  const float* __restrict__ Wv,
                                                  const float* __restrict__ mix1w,
                                                  const float* __restrict__ mix1b,
                                                  const float* __restrict__ mix2w,
                                                  const float* __restrict__ mix2b,
                                                  const float* __restrict__ Wo,
                                                  const float* __restrict__ bo,
                                                  float* __restrict__ ws) {
  __shared__ float scost[4][512];
  __shared__ float aw[32][129];        // [r*8+h][j], padded (4-addr bank spread)
  __shared__ float soc[4][132];        // out_concat, padded, 16B-aligned rows
  __shared__ float sP[8][512];         // partials (phase C: [jh*4+r][c]; D: [seg][r*128+c])
  __shared__ float smix1[8][16], smixb1[8][16], smix2[8][16], smixb2[8];
  __shared__ int   sperm[128];
  __shared__ float sS[256], sQ[256];
  const int t = threadIdx.x;
  const int lane = t & 63;
  const int w = t >> 6;
  const int row0 = blockIdx.x * 4;
  const int b = row0 / 500;

  if (t < 128) {
    sperm[t] = ((const int*)(ws + WS_PERM))[b * 128 + t];
    int h = t >> 4, s = t & 15;
    smix1[h][s]  = mix1w[h * 32 + 16 + s];   // mix1_w[h,1,s] (dot term is zero)
    smixb1[h][s] = mix1b[h * 16 + s];
    smix2[h][s]  = mix2w[h * 16 + s];
    if (t < 8) smixb2[t] = mix2b[t];
  }
  for (int i = t; i < 2048; i += 256) {
    int r = i >> 9, m = i & 511;
    scost[r][m] = (m < 500) ? cost[(size_t)(row0 + r) * 500 + m] : 0.f;
  }
  __syncthreads();

  // phase B: wave w -> row w, all 8 heads
  {
    const int r = w;
    for (int h = 0; h < 8; ++h) {
      float w1e[16], b1e[16], w2e[16];
#pragma unroll
      for (int s = 0; s < 16; ++s) {
        w1e[s] = smix1[h][s]; b1e[s] = smixb1[h][s]; w2e[s] = smix2[h][s];
      }
      const float b2e = smixb2[h];
      float sv[8], mx = -1e30f;
#pragma unroll
      for (int ii = 0; ii < 8; ++ii) {
        int m = ii * 64 + lane;
        float c = scost[r][m];
        float s = b2e;
#pragma unroll
        for (int k = 0; k < 16; ++k) {
          float tt = fmaf(c, w1e[k], b1e[k]);
          tt = fmaxf(tt, 0.f);
          s = fmaf(tt, w2e[k], s);
        }
        if (m >= 500) s = -1e30f;
        sv[ii] = s;
        mx = fmaxf(mx, s);
      }
#pragma unroll
      for (int off = 32; off; off >>= 1) mx = fmaxf(mx, __shfl_xor(mx, off));
      float a0 = 0.f, a1 = 0.f, wsum = 0.f;
#pragma unroll
      for (int ii = 0; ii < 8; ++ii) {
        float e = __expf(sv[ii] - mx);   // masked lanes -> 0
        wsum += e;
        if (ii & 1) a1 += e; else a0 += e;
      }
#pragma unroll
      for (int off = 32; off; off >>= 1) wsum += __shfl_xor(wsum, off);
      float inv = 1.f / wsum;
      aw[r * 8 + h][lane]      = a0 * inv;
      aw[r * 8 + h][64 + lane] = a1 * inv;
    }
  }
  __syncthreads();

  // phase C: oc[r][c] = sum_j aw[r*8+(c>>4)][j] * Wv[perm[j]*128+c]
  {
    const int c  = t & 127;
    const int jh = t >> 7;
    const int h  = c >> 4;
    float acc[4] = {};
    for (int jb = 0; jb < 64; jb += 8) {
      int rows[8];
#pragma unroll
      for (int u = 0; u < 8; ++u) rows[u] = sperm[jh * 64 + jb + u];
      float wv[8];
#pragma unroll
      for (int u = 0; u < 8; ++u) wv[u] = Wv[(size_t)rows[u] * 128 + c];
#pragma unroll
      for (int u = 0; u < 8; ++u) {
        int j = jh * 64 + jb + u;
#pragma unroll
        for (int r = 0; r < 4; ++r)
          acc[r] = fmaf(aw[r * 8 + h][j], wv[u], acc[r]);
      }
    }
#pragma unroll
    for (int r = 0; r < 4; ++r) sP[jh * 4 + r][c] = acc[r];
  }
  __syncthreads();
#pragma unroll
  for (int pass = 0; pass < 2; ++pass) {
    int idx = t + pass * 256;
    int r = idx >> 7, c = idx & 127;
    soc[r][c] = sP[r][c] + sP[4 + r][c];
  }
  __syncthreads();

  // phase D: X1[4][128] = soc @ Wo + bo, k-split 8
  {
    const int cg  = (t & 31) * 4;
    const int seg = t >> 5;
    const int k0  = seg * 16;
    float acc[4][4] = {};
    float av[4][8];
#pragma unroll
    for (int kb = 0; kb < 16; kb += 8) {
      LOAD_ACT8(soc, k0 + kb, av);
      GEMM_BATCH8(Wo + cg, 128, k0 + kb, av, acc);
    }
#pragma unroll
    for (int r = 0; r < 4; ++r)
      *(float4*)&sP[seg][r * 128 + cg] = *(float4*)acc[r];
  }
  __syncthreads();
  float s = 0.f, q = 0.f;
#pragma unroll
  for (int pass = 0; pass < 2; ++pass) {
    int idx = t + pass * 256;
    int col = idx & 127, r = idx >> 7;
    float x = bo[col];
#pragma unroll
    for (int sg = 0; sg < 8; ++sg) x += sP[sg][r * 128 + col];
    ws[WS_X1 + (size_t)(row0 + r) * 128 + col] = x;
    s += x; q = fmaf(x, x, q);
  }
  sS[t] = s; sQ[t] = q;
  __syncthreads();
  if (t < 128) {
    atomicAdd(ws + WS_SUM1 + t, sS[t] + sS[t + 128]);
    atomicAdd(ws + WS_SQ1 + t, sQ[t] + sQ[t + 128]);
  }
}

// ---- BN1 -> o1 -> Y=relu(o1@W1+b1) -> X2=o1+Y@W2+b2 ; BN2 stats ----------
// 250 blocks x 512 thr, 8 rows/block (halves W1/W2 L2 traffic vs 4-row).
__global__ __launch_bounds__(512) void k_ffn(const float* __restrict__ W1,
                                             const float* __restrict__ b1,
                                             const float* __restrict__ g1,
                                             const float* __restrict__ bb1,
                                             const float* __restrict__ W2,
                                             const float* __restrict__ b2,
                                             float* __restrict__ ws) {
  __shared__ float o1[8][128];
  __shared__ float sY[8][512];
  __shared__ float sP[8][8][128];      // 32KB; [kseg][row][col]; first 16KB doubles as GEMM1 partial [8][512]
  __shared__ float sc[128], sh[128];
  __shared__ float sS[512], sQ[512];
  const int t = threadIdx.x;
  const int row0 = blockIdx.x * 8;
  if (t < 128) {
    float m = ws[WS_SUM1 + t] * 5e-4f;
    float v = ws[WS_SQ1 + t] * 5e-4f - m * m;
    float rs = rsqrtf(v + BN_EPS);
    float s = g1[t] * rs;
    sc[t] = s;
    sh[t] = bb1[t] - m * s;
  }
  __syncthreads();
  for (int i = t; i < 1024; i += 512) {
    int r = i >> 7, c = i & 127;
    o1[r][c] = ws[WS_X1 + (size_t)(row0 + r) * 128 + c] * sc[c] + sh[c];
  }
  __syncthreads();
  // GEMM1: thread = cg(128 groups of 4 cols) x kseg(2 x 64k) x rh(2 x 4 rows)
  {
    const int cg   = (t & 127) * 4;
    const int kseg = (t >> 7) & 1;
    const int rh   = t >> 8;
    const int kb0  = kseg * 64;
    float acc[4][4] = {};
    float av[4][8];
#pragma unroll
    for (int k0 = 0; k0 < 64; k0 += 8) {
      LOAD_ACT8((o1 + rh * 4), kb0 + k0, av);
      GEMM_BATCH8(W1 + cg, 512, kb0 + k0, av, acc);
    }
    float* pf = &sP[0][0][0];          // viewed as [8][512]
    if (kseg == 1) {
#pragma unroll
      for (int r = 0; r < 4; ++r)
        *(float4*)(pf + (size_t)(rh * 4 + r) * 512 + cg) = *(float4*)acc[r];
    }
    __syncthreads();
    if (kseg == 0) {
      float4 bv = *(const float4*)(b1 + cg);
#pragma unroll
      for (int r = 0; r < 4; ++r) {
        float4 p = *(float4*)(pf + (size_t)(rh * 4 + r) * 512 + cg);
        float4 y = {fmaxf(acc[r][0] + p.x + bv.x, 0.f),
                    fmaxf(acc[r][1] + p.y + bv.y, 0.f),
                    fmaxf(acc[r][2] + p.z + bv.z, 0.f),
                    fmaxf(acc[r][3] + p.w + bv.w, 0.f)};
        *(float4*)&sY[rh * 4 + r][cg] = y;
      }
    }
  }
  __syncthreads();
  // GEMM2: thread = cg(32 x 4 cols) x kseg(8 x 64k) x rh(2 x 4 rows)
  {
    const int cg   = (t & 31) * 4;
    const int kseg = (t >> 5) & 7;
    const int rh   = t >> 8;
    const int k0   = kseg * 64;
    float acc[4][4] = {};
    float av[4][8];
#pragma unroll
    for (int kb = 0; kb < 64; kb += 8) {
      LOAD_ACT8((sY + rh * 4), k0 + kb, av);
      GEMM_BATCH8(W2 + cg, 128, k0 + kb, av, acc);
    }
    // pf reads finished at the sync after GEMM1 store; safe to overwrite sP
#pragma unroll
    for (int r = 0; r < 4; ++r)
      *(float4*)&sP[kseg][rh * 4 + r][cg] = *(float4*)acc[r];
  }
  __syncthreads();
  float s = 0.f, q = 0.f;
#pragma unroll
  for (int pass = 0; pass < 2; ++pass) {
    int idx = t + pass * 512;
    int col = idx & 127, r = idx >> 7;
    float x = b2[col] + o1[r][col];
#pragma unroll
    for (int sg = 0; sg < 8; ++sg) x += sP[sg][r][col];
    ws[WS_X2 + (size_t)(row0 + r) * 128 + col] = x;
    s += x; q = fmaf(x, x, q);
  }
  sS[t] = s; sQ[t] = q;
  __syncthreads();
  if (t < 128) {
    atomicAdd(ws + WS_SUM2 + t, sS[t] + sS[t + 128] + sS[t + 256] + sS[t + 384]);
    atomicAdd(ws + WS_SQ2 + t, sQ[t] + sQ[t + 128] + sQ[t + 256] + sQ[t + 384]);
  }
}

// ---- out3 = BN2(X2); node = out3 @ Wn_top + demand*u + c0 ; fp32 store ----
__global__ __launch_bounds__(256) void k_final(const float* __restrict__ Wn,
                                               const float* __restrict__ g2,
                                               const float* __restrict__ bb2,
                                               const float* __restrict__ dem,
                                               float* __restrict__ out,
                                               float* __restrict__ ws) {
  __shared__ float o3[4][132];
  __shared__ float sP[8][512];
  __shared__ float sc[128], sh[128];
  const int t = threadIdx.x;
  const int row0 = blockIdx.x * 4;
  if (t < 128) {
    float m = ws[WS_SUM2 + t] * 5e-4f;
    float v = ws[WS_SQ2 + t] * 5e-4f - m * m;
    float rs = rsqrtf(v + BN_EPS);
    float s = g2[t] * rs;
    sc[t] = s;
    sh[t] = bb2[t] - m * s;
  }
  __syncthreads();
  for (int i = t; i < 512; i += 256) {
    int r = i >> 7, c = i & 127;
    o3[r][c] = ws[WS_X2 + (size_t)(row0 + r) * 128 + c] * sc[c] + sh[c];
  }
  __syncthreads();
  const int cg  = (t & 31) * 4;
  const int seg = t >> 5;
  const int k0  = seg * 16;
  float acc[4][4] = {};
  float av[4][8];
#pragma unroll
  for (int kb = 0; kb < 16; kb += 8) {
    LOAD_ACT8(o3, k0 + kb, av);
    GEMM_BATCH8(Wn + cg, 128, k0 + kb, av, acc);
  }
#pragma unroll
  for (int r = 0; r < 4; ++r)
    *(float4*)&sP[seg][r * 128 + cg] = *(float4*)acc[r];
  __syncthreads();
#pragma unroll
  for (int pass = 0; pass < 2; ++pass) {
    int idx = t + pass * 256;
    int col = idx & 127, r = idx >> 7;
    float x = ws[WS_C0 + col] + dem[row0 + r] * ws[WS_U + col];
#pragma unroll
    for (int sg = 0; sg < 8; ++sg) x += sP[sg][r * 128 + col];
    out[(size_t)(row0 + r) * 128 + col] = x;
  }
}

extern "C" void kernel_launch(void* const* d_in, const int* in_sizes, int n_in,
                              void* d_out, int out_size, void* d_ws, size_t ws_size,
                              hipStream_t stream) {
  const float* cost   = (const float*)d_in[0];
  const float* dem    = (const float*)d_in[1];
  const float* rnd    = (const float*)d_in[2];
  // d_in[3] Wq, d_in[4] Wk unused (q == 0)
  const float* Wv     = (const float*)d_in[5];
  const float* mix1w  = (const float*)d_in[6];
  const float* mix1b  = (const float*)d_in[7];
  const float* mix2w  = (const float*)d_in[8];
  const float* mix2b  = (const float*)d_in[9];
  const float* Wo     = (const float*)d_in[10];
  const float* bo     = (const float*)d_in[11];
  const float* W1     = (const float*)d_in[12];
  const float* b1     = (const float*)d_in[13];
  const float* W2     = (const float*)d_in[14];
  const float* b2     = (const float*)d_in[15];
  const float* g1     = (const float*)d_in[16];
  const float* bb1    = (const float*)d_in[17];
  const float* g2     = (const float*)d_in[18];
  const float* bb2    = (const float*)d_in[19];
  const float* Wd     = (const float*)d_in[20];
  const float* bd     = (const float*)d_in[21];
  const float* Wn     = (const float*)d_in[22];
  const float* bnn    = (const float*)d_in[23];
  float* ws  = (float*)d_ws;
  float* out = (float*)d_out;

  hipLaunchKernelGGL(k_init,     dim3(5),   dim3(128), 0, stream, rnd, Wd, bd, Wn, bnn, ws);
  hipLaunchKernelGGL(k_attn_mho, dim3(500), dim3(256), 0, stream, cost, Wv, mix1w, mix1b,
                     mix2w, mix2b, Wo, bo, ws);
  hipLaunchKernelGGL(k_ffn,      dim3(250), dim3(512), 0, stream, W1, b1, g1, bb1, W2, b2, ws);
  hipLaunchKernelGGL(k_final,    dim3(500), dim3(256), 0, stream, Wn, g2, bb2, dem, out, ws);
}

// Round 7
// 54.026 us; speedup vs baseline: 1.9738x; 1.1265x over previous
//
#include <hip/hip_runtime.h>
#include <hip/hip_bf16.h>

// Node_EncodingBlock on MI355X. Inputs fp32, output fp32 (harness compares
// both sides rounded to bf16, 2% tolerance).
// Algebraic simplifications (audited against the reference):
//  - row_emb == 0  =>  q == 0  =>  dot == 0  => Wq, Wk unused.
//  - col_emb one-hot(idx) => v[b,m,h,:] = Wv[idx[b,m], h*16:...], idx[b,m]=perm[b, m&127].
//  - score ms2[b,h,n,m] = g_h(cost[b,n,m]) : per-head scalar MLP of cost only.
//    R7: g_h(c) = A_h·c + B_h + sum_s u_s·|c - r_s|  (relu(x)=(x+|x|)/2; abs is a
//    free VOP3 modifier) -> 2 VALU/term, params precomputed in k_init.
//    No max-pass in softmax (|score| <= ~6, exp(s) safe in fp32).
//  - PV over m=0..499 folds into 128 aggregated softmax weights (idx has period 128).
//  - demand branch: demand*(Wd@Wn_bot) + (bd@Wn_bot + bn_node), precomputed.
// R7: k_attn_mho 512 thr (wave = row x head-half), cost hoisted to regs once,
// head params from L2 (VMEM) not LDS.

#define BN_EPS 1e-5f
// ws layout (float offsets)
#define WS_X1    256000     // [2000][128]
#define WS_X2    512000     // [2000][128]
#define WS_PERM  768000     // [4][128] int
#define WS_U     768512
#define WS_C0    768640
#define WS_SUM1  768768
#define WS_SQ1   768896
#define WS_SUM2  769024
#define WS_SQ2   769152
#define WS_MLPU  769280     // [8][16] u_s
#define WS_MLPR  769408     // [8][16] r_s
#define WS_MLPAB 769536     // [8][2]  A,B

// ---- init: argsort perm, demand vectors, BN zeros, MLP abs-form params ----
__global__ __launch_bounds__(128) void k_init(const float* __restrict__ rnd,
                                              const float* __restrict__ Wd,
                                              const float* __restrict__ bd,
                                              const float* __restrict__ Wn,
                                              const float* __restrict__ bnn,
                                              const float* __restrict__ mix1w,
                                              const float* __restrict__ mix1b,
                                              const float* __restrict__ mix2w,
                                              const float* __restrict__ mix2b,
                                              float* __restrict__ ws) {
  const int t = threadIdx.x;
  const int b = blockIdx.x;
  if (b < 4) {
    __shared__ float v[128];
    __shared__ int ps[128];
    float vt = rnd[b * 128 + t];
    v[t] = vt;
    __syncthreads();
    int rank = 0;
    for (int j = 0; j < 128; ++j) {
      float vj = v[j];
      rank += (vj < vt) || (vj == vt && j < t);
    }
    ps[rank] = t;
    __syncthreads();
    ((int*)(ws + WS_PERM))[b * 128 + t] = ps[t];
  } else if (b == 4) {
    float u = 0.f, c0 = 0.f;
#pragma unroll 8
    for (int e = 0; e < 128; ++e) {
      float wn = Wn[(128 + e) * 128 + t];
      u  = fmaf(Wd[e], wn, u);
      c0 = fmaf(bd[e], wn, c0);
    }
    ws[WS_U + t]  = u;
    ws[WS_C0 + t] = c0 + bnn[t];
    ws[WS_SUM1 + t] = 0.f; ws[WS_SQ1 + t] = 0.f;
    ws[WS_SUM2 + t] = 0.f; ws[WS_SQ2 + t] = 0.f;
  } else {
    // abs-form MLP params: g(c) = A c + B + sum u_s |c - r_s|
    const int h = t >> 4, s = t & 15;
    float w1  = mix1w[h * 32 + 16 + s];   // mix1_w[h,1,s] (dot input is zero)
    float b1v = mix1b[h * 16 + s];
    float w2  = mix2w[h * 16 + s];
    bool tiny = fabsf(w1) < 1e-20f;
    float us = tiny ? 0.f : 0.5f * w2 * fabsf(w1);
    float rs = tiny ? 0.f : -b1v / w1;
    float Ap = 0.5f * w2 * w1;
    float Bp = 0.5f * w2 * b1v + (tiny ? 0.5f * w2 * fabsf(b1v) : 0.f);
    ws[WS_MLPU + h * 16 + s] = us;
    ws[WS_MLPR + h * 16 + s] = rs;
#pragma unroll
    for (int off = 1; off < 16; off <<= 1) {
      Ap += __shfl_xor(Ap, off);
      Bp += __shfl_xor(Bp, off);
    }
    if (s == 0) {
      ws[WS_MLPAB + h * 2]     = Ap;
      ws[WS_MLPAB + h * 2 + 1] = Bp + mix2b[h];
    }
  }
}

// Batched GEMM micro-steps (explicit reg arrays -> independent loads, ILP).
#define GEMM_BATCH8(WPTR, LDW, KIDX, ACT2D, ACC)                        \
  {                                                                     \
    float4 w[8];                                                        \
    _Pragma("unroll")                                                   \
    for (int u = 0; u < 8; ++u)                                         \
      w[u] = *(const float4*)((WPTR) + (size_t)((KIDX) + u) * (LDW));   \
    _Pragma("unroll")                                                   \
    for (int u = 0; u < 8; ++u) {                                       \
      _Pragma("unroll")                                                 \
      for (int r = 0; r < 4; ++r) {                                     \
        float a = ACT2D[r][u];                                          \
        ACC[r][0] = fmaf(a, w[u].x, ACC[r][0]);                         \
        ACC[r][1] = fmaf(a, w[u].y, ACC[r][1]);                         \
        ACC[r][2] = fmaf(a, w[u].z, ACC[r][2]);                         \
        ACC[r][3] = fmaf(a, w[u].w, ACC[r][3]);                         \
      }                                                                 \
    }                                                                   \
  }

#define LOAD_ACT8(SRC2D, KIDX, ACT2D)                                   \
  {                                                                     \
    _Pragma("unroll")                                                   \
    for (int r = 0; r < 4; ++r) {                                       \
      float4 x = *(const float4*)&SRC2D[r][(KIDX)];                     \
      float4 y = *(const float4*)&SRC2D[r][(KIDX) + 4];                 \
      ACT2D[r][0] = x.x; ACT2D[r][1] = x.y; ACT2D[r][2] = x.z;          \
      ACT2D[r][3] = x.w; ACT2D[r][4] = y.x; ACT2D[r][5] = y.y;          \
      ACT2D[r][6] = y.z; ACT2D[r][7] = y.w;                             \
    }                                                                   \
  }

#define GEMM_BATCH8_R2(WPTR, LDW, KIDX, ACT2D, ACC)                     \
  {                                                                     \
    float4 w[8];                                                        \
    _Pragma("unroll")                                                   \
    for (int u = 0; u < 8; ++u)                                         \
      w[u] = *(const float4*)((WPTR) + (size_t)((KIDX) + u) * (LDW));   \
    _Pragma("unroll")                                                   \
    for (int u = 0; u < 8; ++u) {                                       \
      _Pragma("unroll")                                                 \
      for (int r = 0; r < 2; ++r) {                                     \
        float a = ACT2D[r][u];                                          \
        ACC[r][0] = fmaf(a, w[u].x, ACC[r][0]);                         \
        ACC[r][1] = fmaf(a, w[u].y, ACC[r][1]);                         \
        ACC[r][2] = fmaf(a, w[u].z, ACC[r][2]);                         \
        ACC[r][3] = fmaf(a, w[u].w, ACC[r][3]);                         \
      }                                                                 \
    }                                                                   \
  }

// ---- fused attention + multi_head_combine + BN1 stats --------------------
// 500 blocks x 512 thr, 4 rows/block. Wave = (row, head-half): 4 heads each.
__global__ __launch_bounds__(512, 4) void k_attn_mho(const float* __restrict__ cost,
                                                     const float* __restrict__ Wv,
                                                     const float* __restrict__ Wo,
                                                     const float* __restrict__ bo,
                                                     float* __restrict__ ws) {
  __shared__ float scost[4][512];
  __shared__ float aw[32][132];   // [r*8+h][j]; 132: 16B-aligned rows, bank-spread
  __shared__ float soc[4][132];
  __shared__ float sP[8][512];
  __shared__ int   sperm[128];
  __shared__ float sS[512], sQ[512];
  const int t = threadIdx.x;
  const int lane = t & 63;
  const int row0 = blockIdx.x * 4;
  const int b = row0 / 500;

  // phase A: stage cost rows (float4; rows are 16B-aligned: 500*4B = 125*16B)
  if (t < 500) {
    int rr = t / 125, i4 = t - rr * 125;
    *(float4*)&scost[rr][i4 * 4] =
        *(const float4*)(cost + (size_t)(row0 + rr) * 500 + i4 * 4);
  } else {
    int idx = t - 500;               // 12 threads zero scost[*][500..512)
    int rr = idx & 3, m0 = 500 + (idx >> 2) * 4;
    *(float4*)&scost[rr][m0] = float4{0.f, 0.f, 0.f, 0.f};
  }
  if (t < 128) sperm[t] = ((const int*)(ws + WS_PERM))[b * 128 + t];
  __syncthreads();

  // phase B: wave (r, h0): scores + softmax -> aggregated weights aw
  {
    const int wid = t >> 6;
    const int r  = wid & 3;
    const int h0 = (wid >> 2) * 4;
    float cv[8];
#pragma unroll
    for (int ii = 0; ii < 8; ++ii) cv[ii] = scost[r][ii * 64 + lane];
    for (int h = h0; h < h0 + 4; ++h) {
      float4 uq[4], rq[4];
#pragma unroll
      for (int q = 0; q < 4; ++q) {
        uq[q] = *(const float4*)(ws + WS_MLPU + h * 16 + q * 4);
        rq[q] = *(const float4*)(ws + WS_MLPR + h * 16 + q * 4);
      }
      const float A  = ws[WS_MLPAB + h * 2];
      const float Bc = ws[WS_MLPAB + h * 2 + 1];
      float wsum = 0.f, a0 = 0.f, a1 = 0.f;
#pragma unroll
      for (int ii = 0; ii < 8; ++ii) {
        float c = cv[ii];
        float s = fmaf(c, A, Bc);
#pragma unroll
        for (int q = 0; q < 4; ++q) {
          s = fmaf(fabsf(c - rq[q].x), uq[q].x, s);
          s = fmaf(fabsf(c - rq[q].y), uq[q].y, s);
          s = fmaf(fabsf(c - rq[q].z), uq[q].z, s);
          s = fmaf(fabsf(c - rq[q].w), uq[q].w, s);
        }
        if (ii == 7) s = (lane < 52) ? s : -1e30f;   // mask m >= 500
        float e = __expf(s);
        wsum += e;
        if (ii & 1) a1 += e; else a0 += e;
      }
#pragma unroll
      for (int off = 32; off; off >>= 1) wsum += __shfl_xor(wsum, off);
      float inv = 1.f / wsum;
      aw[r * 8 + h][lane]      = a0 * inv;
      aw[r * 8 + h][64 + lane] = a1 * inv;
    }
  }
  __syncthreads();

  // phase C: oc[r][c] = sum_j aw[r*8+(c>>4)][j] * Wv[perm[j]][c]; j-split 4
  {
    const int c  = t & 127;
    const int jh = t >> 7;            // 0..3, 32 j each
    const int h  = c >> 4;
    float acc4[4] = {0.f, 0.f, 0.f, 0.f};
    for (int jb = jh * 32; jb < jh * 32 + 32; jb += 8) {
      int rows[8];
#pragma unroll
      for (int u = 0; u < 8; ++u) rows[u] = sperm[jb + u];
      float wv8[8];
#pragma unroll
      for (int u = 0; u < 8; ++u) wv8[u] = Wv[(size_t)rows[u] * 128 + c];
#pragma unroll
      for (int r = 0; r < 4; ++r) {
        float4 aa = *(const float4*)&aw[r * 8 + h][jb];
        float4 ab = *(const float4*)&aw[r * 8 + h][jb + 4];
        acc4[r] = fmaf(aa.x, wv8[0], acc4[r]);
        acc4[r] = fmaf(aa.y, wv8[1], acc4[r]);
        acc4[r] = fmaf(aa.z, wv8[2], acc4[r]);
        acc4[r] = fmaf(aa.w, wv8[3], acc4[r]);
        acc4[r] = fmaf(ab.x, wv8[4], acc4[r]);
        acc4[r] = fmaf(ab.y, wv8[5], acc4[r]);
        acc4[r] = fmaf(ab.z, wv8[6], acc4[r]);
        acc4[r] = fmaf(ab.w, wv8[7], acc4[r]);
      }
    }
#pragma unroll
    for (int r = 0; r < 4; ++r) sP[jh][r * 128 + c] = acc4[r];
  }
  __syncthreads();
  {
    int r = t >> 7, c = t & 127;
    soc[r][c] = sP[0][r * 128 + c] + sP[1][r * 128 + c] +
                sP[2][r * 128 + c] + sP[3][r * 128 + c];
  }
  __syncthreads();

  // phase D: X1[4][128] = soc @ Wo + bo; k-split 8 x row-half 2
  {
    const int cg  = (t & 31) * 4;
    const int seg = (t >> 5) & 7;
    const int rh  = t >> 8;           // 0..1 -> rows rh*2..rh*2+1
    const int k0  = seg * 16;
    float acc[2][4] = {};
    float av[2][8];
#pragma unroll
    for (int kb = 0; kb < 16; kb += 8) {
#pragma unroll
      for (int r = 0; r < 2; ++r) {
        float4 x = *(const float4*)&soc[rh * 2 + r][k0 + kb];
        float4 y = *(const float4*)&soc[rh * 2 + r][k0 + kb + 4];
        av[r][0] = x.x; av[r][1] = x.y; av[r][2] = x.z; av[r][3] = x.w;
        av[r][4] = y.x; av[r][5] = y.y; av[r][6] = y.z; av[r][7] = y.w;
      }
      GEMM_BATCH8_R2(Wo + cg, 128, k0 + kb, av, acc);
    }
#pragma unroll
    for (int r = 0; r < 2; ++r)
      *(float4*)&sP[seg][(rh * 2 + r) * 128 + cg] = *(float4*)acc[r];
  }
  __syncthreads();
  {
    int r = t >> 7, col = t & 127;
    float x = bo[col];
#pragma unroll
    for (int sg = 0; sg < 8; ++sg) x += sP[sg][r * 128 + col];
    ws[WS_X1 + (size_t)(row0 + r) * 128 + col] = x;
    sS[t] = x; sQ[t] = x * x;
  }
  __syncthreads();
  if (t < 128) {
    atomicAdd(ws + WS_SUM1 + t, sS[t] + sS[t + 128] + sS[t + 256] + sS[t + 384]);
    atomicAdd(ws + WS_SQ1 + t, sQ[t] + sQ[t + 128] + sQ[t + 256] + sQ[t + 384]);
  }
}

// ---- BN1 -> o1 -> Y=relu(o1@W1+b1) -> X2=o1+Y@W2+b2 ; BN2 stats ----------
// 250 blocks x 512 thr, 8 rows/block.
__global__ __launch_bounds__(512) void k_ffn(const float* __restrict__ W1,
                                             const float* __restrict__ b1,
                                             const float* __restrict__ g1,
                                             const float* __restrict__ bb1,
                                             const float* __restrict__ W2,
                                             const float* __restrict__ b2,
                                             float* __restrict__ ws) {
  __shared__ float o1[8][128];
  __shared__ float sY[8][512];
  __shared__ float sP[8][8][128];
  __shared__ float sc[128], sh[128];
  __shared__ float sS[512], sQ[512];
  const int t = threadIdx.x;
  const int row0 = blockIdx.x * 8;
  if (t < 128) {
    float m = ws[WS_SUM1 + t] * 5e-4f;
    float v = ws[WS_SQ1 + t] * 5e-4f - m * m;
    float rs = rsqrtf(v + BN_EPS);
    float s = g1[t] * rs;
    sc[t] = s;
    sh[t] = bb1[t] - m * s;
  }
  __syncthreads();
  for (int i = t; i < 1024; i += 512) {
    int r = i >> 7, c = i & 127;
    o1[r][c] = ws[WS_X1 + (size_t)(row0 + r) * 128 + c] * sc[c] + sh[c];
  }
  __syncthreads();
  // GEMM1: cg(128 x 4 cols) x kseg(2 x 64k) x rh(2 x 4 rows)
  {
    const int cg   = (t & 127) * 4;
    const int kseg = (t >> 7) & 1;
    const int rh   = t >> 8;
    const int kb0  = kseg * 64;
    float acc[4][4] = {};
    float av[4][8];
#pragma unroll
    for (int k0 = 0; k0 < 64; k0 += 8) {
      LOAD_ACT8((o1 + rh * 4), kb0 + k0, av);
      GEMM_BATCH8(W1 + cg, 512, kb0 + k0, av, acc);
    }
    float* pf = &sP[0][0][0];          // viewed as [8][512]
    if (kseg == 1) {
#pragma unroll
      for (int r = 0; r < 4; ++r)
        *(float4*)(pf + (size_t)(rh * 4 + r) * 512 + cg) = *(float4*)acc[r];
    }
    __syncthreads();
    if (kseg == 0) {
      float4 bv = *(const float4*)(b1 + cg);
#pragma unroll
      for (int r = 0; r < 4; ++r) {
        float4 p = *(float4*)(pf + (size_t)(rh * 4 + r) * 512 + cg);
        float4 y = {fmaxf(acc[r][0] + p.x + bv.x, 0.f),
                    fmaxf(acc[r][1] + p.y + bv.y, 0.f),
                    fmaxf(acc[r][2] + p.z + bv.z, 0.f),
                    fmaxf(acc[r][3] + p.w + bv.w, 0.f)};
        *(float4*)&sY[rh * 4 + r][cg] = y;
      }
    }
  }
  __syncthreads();
  // GEMM2: cg(32 x 4 cols) x kseg(8 x 64k) x rh(2 x 4 rows)
  {
    const int cg   = (t & 31) * 4;
    const int kseg = (t >> 5) & 7;
    const int rh   = t >> 8;
    const int k0   = kseg * 64;
    float acc[4][4] = {};
    float av[4][8];
#pragma unroll
    for (int kb = 0; kb < 64; kb += 8) {
      LOAD_ACT8((sY + rh * 4), k0 + kb, av);
      GEMM_BATCH8(W2 + cg, 128, k0 + kb, av, acc);
    }
#pragma unroll
    for (int r = 0; r < 4; ++r)
      *(float4*)&sP[kseg][rh * 4 + r][cg] = *(float4*)acc[r];
  }
  __syncthreads();
  float s = 0.f, q = 0.f;
#pragma unroll
  for (int pass = 0; pass < 2; ++pass) {
    int idx = t + pass * 512;
    int col = idx & 127, r = idx >> 7;
    float x = b2[col] + o1[r][col];
#pragma unroll
    for (int sg = 0; sg < 8; ++sg) x += sP[sg][r][col];
    ws[WS_X2 + (size_t)(row0 + r) * 128 + col] = x;
    s += x; q = fmaf(x, x, q);
  }
  sS[t] = s; sQ[t] = q;
  __syncthreads();
  if (t < 128) {
    atomicAdd(ws + WS_SUM2 + t, sS[t] + sS[t + 128] + sS[t + 256] + sS[t + 384]);
    atomicAdd(ws + WS_SQ2 + t, sQ[t] + sQ[t + 128] + sQ[t + 256] + sQ[t + 384]);
  }
}

// ---- out3 = BN2(X2); node = out3 @ Wn_top + demand*u + c0 ; fp32 store ----
__global__ __launch_bounds__(256) void k_final(const float* __restrict__ Wn,
                                               const float* __restrict__ g2,
                                               const float* __restrict__ bb2,
                                               const float* __restrict__ dem,
                                               float* __restrict__ out,
                                               float* __restrict__ ws) {
  __shared__ float o3[4][132];
  __shared__ float sP[8][512];
  __shared__ float sc[128], sh[128];
  const int t = threadIdx.x;
  const int row0 = blockIdx.x * 4;
  if (t < 128) {
    float m = ws[WS_SUM2 + t] * 5e-4f;
    float v = ws[WS_SQ2 + t] * 5e-4f - m * m;
    float rs = rsqrtf(v + BN_EPS);
    float s = g2[t] * rs;
    sc[t] = s;
    sh[t] = bb2[t] - m * s;
  }
  __syncthreads();
  for (int i = t; i < 512; i += 256) {
    int r = i >> 7, c = i & 127;
    o3[r][c] = ws[WS_X2 + (size_t)(row0 + r) * 128 + c] * sc[c] + sh[c];
  }
  __syncthreads();
  const int cg  = (t & 31) * 4;
  const int seg = t >> 5;
  const int k0  = seg * 16;
  float acc[4][4] = {};
  float av[4][8];
#pragma unroll
  for (int kb = 0; kb < 16; kb += 8) {
    LOAD_ACT8(o3, k0 + kb, av);
    GEMM_BATCH8(Wn + cg, 128, k0 + kb, av, acc);
  }
#pragma unroll
  for (int r = 0; r < 4; ++r)
    *(float4*)&sP[seg][r * 128 + cg] = *(float4*)acc[r];
  __syncthreads();
#pragma unroll
  for (int pass = 0; pass < 2; ++pass) {
    int idx = t + pass * 256;
    int col = idx & 127, r = idx >> 7;
    float x = ws[WS_C0 + col] + dem[row0 + r] * ws[WS_U + col];
#pragma unroll
    for (int sg = 0; sg < 8; ++sg) x += sP[sg][r * 128 + col];
    out[(size_t)(row0 + r) * 128 + col] = x;
  }
}

extern "C" void kernel_launch(void* const* d_in, const int* in_sizes, int n_in,
                              void* d_out, int out_size, void* d_ws, size_t ws_size,
                              hipStream_t stream) {
  const float* cost   = (const float*)d_in[0];
  const float* dem    = (const float*)d_in[1];
  const float* rnd    = (const float*)d_in[2];
  // d_in[3] Wq, d_in[4] Wk unused (q == 0)
  const float* Wv     = (const float*)d_in[5];
  const float* mix1w  = (const float*)d_in[6];
  const float* mix1b  = (const float*)d_in[7];
  const float* mix2w  = (const float*)d_in[8];
  const float* mix2b  = (const float*)d_in[9];
  const float* Wo     = (const float*)d_in[10];
  const float* bo     = (const float*)d_in[11];
  const float* W1     = (const float*)d_in[12];
  const float* b1     = (const float*)d_in[13];
  const float* W2     = (const float*)d_in[14];
  const float* b2     = (const float*)d_in[15];
  const float* g1     = (const float*)d_in[16];
  const float* bb1    = (const float*)d_in[17];
  const float* g2     = (const float*)d_in[18];
  const float* bb2    = (const float*)d_in[19];
  const float* Wd     = (const float*)d_in[20];
  const float* bd     = (const float*)d_in[21];
  const float* Wn     = (const float*)d_in[22];
  const float* bnn    = (const float*)d_in[23];
  float* ws  = (float*)d_ws;
  float* out = (float*)d_out;

  hipLaunchKernelGGL(k_init,     dim3(6),   dim3(128), 0, stream, rnd, Wd, bd, Wn, bnn,
                     mix1w, mix1b, mix2w, mix2b, ws);
  hipLaunchKernelGGL(k_attn_mho, dim3(500), dim3(512), 0, stream, cost, Wv, Wo, bo, ws);
  hipLaunchKernelGGL(k_ffn,      dim3(250), dim3(512), 0, stream, W1, b1, g1, bb1, W2, b2, ws);
  hipLaunchKernelGGL(k_final,    dim3(500), dim3(256), 0, stream, Wn, g2, bb2, dem, out, ws);
}